// Round 10
// baseline (130.959 us; speedup 1.0000x reference)
//
#include <hip/hip_runtime.h>

// Problem constants:
//   B=16, P1=25, P2=24 -> S=600 tokens; E=(8,8,16)=1024; heads (2,2,4)=16, head_dim 64
#define S   600
#define NB  16
#define NH  16
#define HD  64
// Q pre-scale: (head_dim)^-0.5 * log2(e): scores in log2 domain -> softmax uses exp2.
#define QSCALE 0.18033688011112042f

#define LDT 20   // TCL intermediate row stride (floats)

typedef _Float16 f16x8 __attribute__((ext_vector_type(8)));
typedef float f32x4 __attribute__((ext_vector_type(4)));

// ---------------------------------------------------------------------------
// Kernel A: TCL for q,k,v — wave-per-token, barrier-free (unchanged from R9).
// ---------------------------------------------------------------------------
__global__ __launch_bounds__(256) void tcl_qkv_kernel(
    const float* __restrict__ x,
    const float* __restrict__ qw0, const float* __restrict__ qw1,
    const float* __restrict__ qw2, const float* __restrict__ qb,
    const float* __restrict__ kw0, const float* __restrict__ kw1,
    const float* __restrict__ kw2, const float* __restrict__ kb,
    const float* __restrict__ vw0, const float* __restrict__ vw1,
    const float* __restrict__ vw2, const float* __restrict__ vb,
    _Float16* __restrict__ Qh, _Float16* __restrict__ Kh,
    _Float16* __restrict__ Vh)
{
  __shared__ __align__(16) float t1s[4][64 * LDT];
  __shared__ __align__(16) float t2s[4][64 * LDT];

  const int tid = threadIdx.x;
  const int wv = tid >> 6, lane = tid & 63;
  const int tok = blockIdx.x * 4 + wv;
  const int b = tok / S, t = tok - b * S;
  const int q = lane >> 3, zp = lane & 7;
  float* __restrict__ t1 = t1s[wv];
  float* __restrict__ t2 = t2s[wv];

  float2 xc[8];
  #pragma unroll
  for (int xx = 0; xx < 8; ++xx)
    xc[xx] = *(const float2*)&x[(size_t)tok * 1024 + xx * 128 + q * 16 + zp * 2];

  const int xs = lane >> 4;
  const int h1 = (lane >> 3) & 1;
  const int cc = lane & 7;
  const int ys = cc >> 1, h2 = cc & 1;

  const float* W0[3] = {qw0, kw0, vw0};
  const float* W1[3] = {qw1, kw1, vw1};
  const float* W2[3] = {qw2, kw2, vw2};
  const float* BB[3] = {qb, kb, vb};
  _Float16* OUT[3] = {Qh, Kh, Vh};

  #pragma unroll
  for (int p = 0; p < 3; ++p) {
    const float* __restrict__ w0 = W0[p];
    const float* __restrict__ w1 = W1[p];
    const float* __restrict__ w2 = W2[p];
    const float* __restrict__ bb = BB[p];
    _Float16* __restrict__ op = OUT[p];

    #pragma unroll
    for (int a = 0; a < 8; ++a) {
      float2 r = make_float2(0.f, 0.f);
      #pragma unroll
      for (int xx = 0; xx < 8; ++xx) {
        const float w = w0[a * 8 + xx];
        r.x = fmaf(w, xc[xx].x, r.x);
        r.y = fmaf(w, xc[xx].y, r.y);
      }
      *(float2*)&t1[(a * 8 + q) * LDT + zp * 2] = r;
    }
    __builtin_amdgcn_wave_barrier();

    float2 t1r[8];
    #pragma unroll
    for (int y = 0; y < 8; ++y)
      t1r[y] = *(float2*)&t1[(q * 8 + y) * LDT + zp * 2];
    #pragma unroll
    for (int c = 0; c < 8; ++c) {
      float2 r = make_float2(0.f, 0.f);
      #pragma unroll
      for (int y = 0; y < 8; ++y) {
        const float w = w1[c * 8 + y];
        r.x = fmaf(w, t1r[y].x, r.x);
        r.y = fmaf(w, t1r[y].y, r.y);
      }
      *(float2*)&t2[(q * 8 + c) * LDT + zp * 2] = r;
    }
    __builtin_amdgcn_wave_barrier();

    float t2r[16];
    #pragma unroll
    for (int k = 0; k < 4; ++k)
      *(float4*)&t2r[k * 4] = *(float4*)&t2[lane * LDT + k * 4];
    float bias[16];
    #pragma unroll
    for (int k = 0; k < 4; ++k)
      *(float4*)&bias[k * 4] = *(const float4*)&bb[lane * 16 + k * 4];
    float o[16];
    #pragma unroll
    for (int d = 0; d < 16; ++d) {
      float acc = 0.f;
      #pragma unroll
      for (int j = 0; j < 16; ++j)
        acc = fmaf(w2[d * 16 + j], t2r[j], acc);
      o[d] = acc + bias[d];
    }
    const float sc = (p == 0) ? QSCALE : 1.0f;
    #pragma unroll
    for (int h3 = 0; h3 < 4; ++h3) {
      union { _Float16 hh[4]; uint2 u; } pk;
      #pragma unroll
      for (int z = 0; z < 4; ++z)
        pk.hh[z] = (_Float16)(o[4 * z + h3] * sc);
      const int head = h1 * 8 + h2 * 4 + h3;
      *(uint2*)&op[((size_t)((b * NH + head) * S + t)) * HD + xs * 16 + ys * 4]
          = pk.u;
    }
    __builtin_amdgcn_wave_barrier();
  }
}

// ---------------------------------------------------------------------------
// Kernel A2: V [b,h,600,64] f16 -> Vt [b,h,64,600] f16 (unchanged).
// ---------------------------------------------------------------------------
__global__ __launch_bounds__(256) void vtrans_kernel(
    const _Float16* __restrict__ Vh, _Float16* __restrict__ Vt)
{
  __shared__ __align__(16) _Float16 tile[64 * 64];
  const int tid = threadIdx.x;
  const int tt = blockIdx.x, h = blockIdx.y, b = blockIdx.z;
  const size_t rbase = (size_t)(b * NH + h) * S * HD;
  const size_t wbase = (size_t)(b * NH + h) * HD * S;
  const int t0 = tt * 64;

  #pragma unroll
  for (int hp = 0; hp < 2; ++hp) {
    const int u = hp * 256 + tid;
    const int r = u >> 3, ch = u & 7;
    f16x8 v = {0, 0, 0, 0, 0, 0, 0, 0};
    if (t0 + r < S) v = *(const f16x8*)&Vh[rbase + (size_t)(t0 + r) * HD + ch * 8];
    *(f16x8*)&tile[r * 64 + ((ch ^ ((r ^ (r >> 3)) & 7)) * 8)] = v;
  }
  __syncthreads();
  #pragma unroll
  for (int hp = 0; hp < 2; ++hp) {
    const int w = hp * 256 + tid;
    const int d = w >> 3, tc = w & 7;
    if (t0 + tc * 8 + 8 <= S) {
      const int cd = d >> 3;
      union { _Float16 hh[8]; f16x8 v; } g;
      #pragma unroll
      for (int e = 0; e < 8; ++e) {
        const int r = tc * 8 + e;
        g.hh[e] = tile[r * 64 + ((cd ^ ((r ^ (r >> 3)) & 7)) * 8) + (d & 7)];
      }
      *(f16x8*)&Vt[wbase + (size_t)d * S + t0 + tc * 8] = g.v;
    }
  }
}

// ---------------------------------------------------------------------------
// Kernel B: MFMA flash attention, 128 q-rows per block (2 fragments/wave).
// K/V staging, K-frag and V-frag LDS reads, and barriers are shared by both
// fragments (each kf/vf read feeds two MFMAs) — halves per-work LDS/staging/
// barrier overhead vs R9. P relay = 32 rows/wave (LDS 32 KB). VGPR pinned
// <=128 via __launch_bounds__(256,4) (4 waves/SIMD band).
// ---------------------------------------------------------------------------
template<bool TAIL, int NMT>
__device__ __forceinline__ void softmax_frag(
    f32x4 (&accs)[NMT], float& mrow, float& lrow, f32x4 (&po)[4],
    _Float16* __restrict__ Pw, const int prow, const int lg)
{
  float sv[NMT][4];
  #pragma unroll
  for (int mt = 0; mt < NMT; ++mt)
    #pragma unroll
    for (int r = 0; r < 4; ++r) {
      float s = accs[mt][r];
      if (TAIL && mt == 1) s = (lg < 2) ? s : -1e30f;  // keys >= 600 dead
      sv[mt][r] = s;
    }
  float tmax;
  {
    const float a = fmaxf(fmaxf(sv[0][0], sv[0][1]), fmaxf(sv[0][2], sv[0][3]));
    const float b = fmaxf(fmaxf(sv[1][0], sv[1][1]), fmaxf(sv[1][2], sv[1][3]));
    if (TAIL) {
      tmax = fmaxf(a, b);
    } else {
      const float c2 = fmaxf(fmaxf(sv[2][0], sv[2][1]), fmaxf(sv[2][2], sv[2][3]));
      const float d2 = fmaxf(fmaxf(sv[3][0], sv[3][1]), fmaxf(sv[3][2], sv[3][3]));
      tmax = fmaxf(fmaxf(a, b), fmaxf(c2, d2));
    }
  }
  tmax = fmaxf(tmax, __shfl_xor(tmax, 16));
  tmax = fmaxf(tmax, __shfl_xor(tmax, 32));
  // defer-max: skip O/l rescale while tile max is within 2^11 of running max
  if (!__all(tmax - mrow <= 11.0f)) {
    const float mn = fmaxf(mrow, tmax);
    const float corr = __builtin_amdgcn_exp2f(mrow - mn);
    lrow *= corr;
    #pragma unroll
    for (int dt = 0; dt < 4; ++dt) {
      po[dt][0] *= corr; po[dt][1] *= corr;
      po[dt][2] *= corr; po[dt][3] *= corr;
    }
    mrow = mn;
  }
  float rs = 0.f;
  #pragma unroll
  for (int mt = 0; mt < NMT; ++mt) {
    const float e0 = __builtin_amdgcn_exp2f(sv[mt][0] - mrow);
    const float e1 = __builtin_amdgcn_exp2f(sv[mt][1] - mrow);
    const float e2 = __builtin_amdgcn_exp2f(sv[mt][2] - mrow);
    const float e3 = __builtin_amdgcn_exp2f(sv[mt][3] - mrow);
    rs += (e0 + e1) + (e2 + e3);
    union { _Float16 hh[4]; unsigned long long u; } pk;
    pk.hh[0] = (_Float16)e0; pk.hh[1] = (_Float16)e1;
    pk.hh[2] = (_Float16)e2; pk.hh[3] = (_Float16)e3;
    const int idx = prow * 64 + (((2 * mt + (lg >> 1)) ^ (prow & 7)) * 8)
                  + (lg & 1) * 4;
    *(unsigned long long*)&Pw[idx] = pk.u;
  }
  rs += __shfl_xor(rs, 16);
  rs += __shfl_xor(rs, 32);
  lrow += rs;
}

template<bool TAIL>
__device__ __forceinline__ void attn_step2(
    const _Float16* __restrict__ Ks, const _Float16* __restrict__ Vs,
    _Float16* __restrict__ Pw,
    const f16x8 qfA0, const f16x8 qfA1, const f16x8 qfB0, const f16x8 qfB1,
    f32x4 (&poA)[4], f32x4 (&poB)[4],
    float& mA, float& lA, float& mB, float& lB,
    const int lr, const int lg)
{
  constexpr int NMT = TAIL ? 2 : 4;
  f32x4 aA[NMT], aB[NMT];
  #pragma unroll
  for (int mt = 0; mt < NMT; ++mt) {
    aA[mt] = (f32x4){0.f, 0.f, 0.f, 0.f};
    aB[mt] = (f32x4){0.f, 0.f, 0.f, 0.f};
  }
  __builtin_amdgcn_s_setprio(1);
  #pragma unroll
  for (int c = 0; c < 2; ++c) {
    const f16x8 qa = c ? qfA1 : qfA0;
    const f16x8 qb = c ? qfB1 : qfB0;
    #pragma unroll
    for (int mt = 0; mt < NMT; ++mt) {
      const int krow = mt * 16 + lr;
      const f16x8 kf = *(const f16x8*)
          &Ks[krow * 64 + (((4 * c + lg) ^ (krow & 7)) * 8)];
      aA[mt] = __builtin_amdgcn_mfma_f32_16x16x32_f16(kf, qa, aA[mt], 0, 0, 0);
      aB[mt] = __builtin_amdgcn_mfma_f32_16x16x32_f16(kf, qb, aB[mt], 0, 0, 0);
    }
  }
  __builtin_amdgcn_s_setprio(0);
  softmax_frag<TAIL, NMT>(aA, mA, lA, poA, Pw, lr, lg);
  softmax_frag<TAIL, NMT>(aB, mB, lB, poB, Pw, 16 + lr, lg);
  __builtin_amdgcn_wave_barrier();   // fence: P writes before P reads (same wave)
  __builtin_amdgcn_s_setprio(1);
  #pragma unroll
  for (int c = 0; c < (TAIL ? 1 : 2); ++c) {
    const f16x8 pfA = *(const f16x8*)
        &Pw[lr * 64 + (((4 * c + lg) ^ (lr & 7)) * 8)];
    const f16x8 pfB = *(const f16x8*)
        &Pw[(16 + lr) * 64 + (((4 * c + lg) ^ ((16 + lr) & 7)) * 8)];
    #pragma unroll
    for (int dt = 0; dt < 4; ++dt) {
      const int drow = dt * 16 + lr;
      const f16x8 vf = *(const f16x8*)
          &Vs[drow * 64 + (((4 * c + lg) ^ (drow & 7)) * 8)];
      poA[dt] = __builtin_amdgcn_mfma_f32_16x16x32_f16(vf, pfA, poA[dt], 0, 0, 0);
      poB[dt] = __builtin_amdgcn_mfma_f32_16x16x32_f16(vf, pfB, poB[dt], 0, 0, 0);
    }
  }
  __builtin_amdgcn_s_setprio(0);
}

__global__ __launch_bounds__(256, 4) void attn_mfma_kernel(
    const _Float16* __restrict__ Qh, const _Float16* __restrict__ Kh,
    const _Float16* __restrict__ Vt, float* __restrict__ Og)
{
  __shared__ __align__(16) union {
    struct {
      _Float16 K[64 * 64];      // swizzled [key][d]        8 KB
      _Float16 V[64 * 64];      // swizzled [d][key]        8 KB
      _Float16 P[4][32 * 64];   // per-wave P relay, 2 frag 16 KB
    } m;                        // 32768 B
    float ot[4][64 * 17];       // epilogue staging (17408 B)
  } sm;

  const int tid = threadIdx.x;
  const int lane = tid & 63;
  const int wv = tid >> 6;
  // XCD-aware decode: 1280 blocks; all 5 q-tiles of a (b,h) co-locate.
  const int id = blockIdx.x;
  const int idx = id >> 3;
  const int bh = (id & 7) * 32 + idx / 5;
  const int qt = idx - (idx / 5) * 5;
  const size_t base  = (size_t)bh * S * HD;
  const size_t vbase = (size_t)bh * HD * S;
  const int lr = lane & 15;
  const int lg = lane >> 4;

  const int qrA_l = qt * 128 + wv * 16 + lr;
  const int qrB_l = qt * 128 + 64 + wv * 16 + lr;
  const int qrA = (qrA_l < S) ? qrA_l : (S - 1);
  const int qrB = (qrB_l < S) ? qrB_l : (S - 1);
  const f16x8 qfA0 = *(const f16x8*)&Qh[base + (size_t)qrA * HD + lg * 8];
  const f16x8 qfA1 = *(const f16x8*)&Qh[base + (size_t)qrA * HD + 32 + lg * 8];
  const f16x8 qfB0 = *(const f16x8*)&Qh[base + (size_t)qrB * HD + lg * 8];
  const f16x8 qfB1 = *(const f16x8*)&Qh[base + (size_t)qrB * HD + 32 + lg * 8];

  f32x4 poA[4] = {{0.f,0.f,0.f,0.f},{0.f,0.f,0.f,0.f},
                  {0.f,0.f,0.f,0.f},{0.f,0.f,0.f,0.f}};
  f32x4 poB[4] = {{0.f,0.f,0.f,0.f},{0.f,0.f,0.f,0.f},
                  {0.f,0.f,0.f,0.f},{0.f,0.f,0.f,0.f}};
  float mA = -1e30f, lA = 0.f, mB = -1e30f, lB = 0.f;

  const int srow = tid >> 3, sch = tid & 7;   // staging: row 0..31, 16B chunk
  const int srow2 = srow + 32;                 // rows 32..63
  const int sswz = ((sch ^ (srow & 7)) * 8);   // srow2&7 == srow&7

  f16x8 kv[2], vv[2];
  auto stage_load_full = [&](int kt) {         // tiles 0..8: no bounds checks
    const int kb = kt * 64;
    kv[0] = *(const f16x8*)&Kh[base + (size_t)(kb + srow ) * HD + sch * 8];
    kv[1] = *(const f16x8*)&Kh[base + (size_t)(kb + srow2) * HD + sch * 8];
    vv[0] = *(const f16x8*)&Vt[vbase + (size_t)srow  * S + kb + sch * 8];
    vv[1] = *(const f16x8*)&Vt[vbase + (size_t)srow2 * S + kb + sch * 8];
  };
  auto stage_load_tail = [&]() {               // kt=9: keys 576..599 valid
    const int kb = 576;
    const f16x8 z = {0, 0, 0, 0, 0, 0, 0, 0};
    kv[0] = (srow < 24)
        ? *(const f16x8*)&Kh[base + (size_t)(kb + srow) * HD + sch * 8] : z;
    kv[1] = z;                                 // rows 32..63 all dead
    if (sch < 3) {                             // key chunks 576..599 (600%8==0)
      vv[0] = *(const f16x8*)&Vt[vbase + (size_t)srow  * S + kb + sch * 8];
      vv[1] = *(const f16x8*)&Vt[vbase + (size_t)srow2 * S + kb + sch * 8];
    } else { vv[0] = z; vv[1] = z; }
  };
  auto stage_write = [&]() {
    *(f16x8*)&sm.m.K[srow  * 64 + sswz] = kv[0];
    *(f16x8*)&sm.m.K[srow2 * 64 + sswz] = kv[1];
    *(f16x8*)&sm.m.V[srow  * 64 + sswz] = vv[0];
    *(f16x8*)&sm.m.V[srow2 * 64 + sswz] = vv[1];
  };

  stage_load_full(0);
  #pragma unroll 1
  for (int kt = 0; kt < 9; ++kt) {
    __syncthreads();                  // prior tile's LDS reads complete
    stage_write();
    if (kt < 8) stage_load_full(kt + 1);   // next loads in flight over compute
    else        stage_load_tail();
    __syncthreads();                  // K/V visible to all waves
    attn_step2<false>(&sm.m.K[0], &sm.m.V[0], &sm.m.P[wv][0],
                      qfA0, qfA1, qfB0, qfB1, poA, poB, mA, lA, mB, lB, lr, lg);
  }
  __syncthreads();
  stage_write();
  __syncthreads();
  attn_step2<true>(&sm.m.K[0], &sm.m.V[0], &sm.m.P[wv][0],
                   qfA0, qfA1, qfB0, qfB1, poA, poB, mA, lA, mB, lB, lr, lg);
  __syncthreads();   // main-loop LDS fully consumed before epilogue reuse

  // epilogue: fragment A then B through the same per-wave ot buffer
  #pragma unroll
  for (int fr = 0; fr < 2; ++fr) {
    const float invl = 1.0f / (fr ? lB : lA);
    #pragma unroll
    for (int dt = 0; dt < 4; ++dt) {
      const f32x4 p = fr ? poB[dt] : poA[dt];
      #pragma unroll
      for (int r = 0; r < 4; ++r)
        sm.ot[wv][(dt * 16 + 4 * lg + r) * 17 + lr] = p[r] * invl;
    }
    __builtin_amdgcn_wave_barrier();   // ot writes before ot reads (same wave)
    #pragma unroll
    for (int ps = 0; ps < 4; ++ps) {
      const int qr = ps * 4 + lg;
      const int gq = qt * 128 + fr * 64 + wv * 16 + qr;
      if (gq < S) {
        const int d0 = lr * 4;
        float4 o4;
        o4.x = sm.ot[wv][(d0 + 0) * 17 + qr];
        o4.y = sm.ot[wv][(d0 + 1) * 17 + qr];
        o4.z = sm.ot[wv][(d0 + 2) * 17 + qr];
        o4.w = sm.ot[wv][(d0 + 3) * 17 + qr];
        *(float4*)&Og[base + (size_t)gq * HD + d0] = o4;
      }
    }
    __builtin_amdgcn_wave_barrier();   // ot reads done before next frag writes
  }
}

// ---------------------------------------------------------------------------
// Kernel C: output TCL — wave-per-token, barrier-free (unchanged from R9).
// ---------------------------------------------------------------------------
__global__ __launch_bounds__(256) void tcl_out_kernel(
    const float* __restrict__ Og,
    const float* __restrict__ ow0, const float* __restrict__ ow1,
    const float* __restrict__ ow2, const float* __restrict__ ob,
    float* __restrict__ out)
{
  __shared__ __align__(16) float t1s[4][64 * LDT];
  __shared__ __align__(16) float t2s[4][64 * LDT];

  const int tid = threadIdx.x;
  const int wv = tid >> 6, lane = tid & 63;
  const int tok = blockIdx.x * 4 + wv;
  const int b = tok / S, t = tok - b * S;
  const int q = lane >> 3, zp = lane & 7;
  float* __restrict__ t1 = t1s[wv];
  float* __restrict__ t2 = t2s[wv];

  float2 xc[8];
  {
    const int h2g = q & 1, yg = q >> 1;
    const int h3g = 2 * (zp & 1), zg = zp >> 1;
    #pragma unroll
    for (int xx = 0; xx < 8; ++xx) {
      const int headb = (xx & 1) * 8 + h2g * 4 + h3g;
      const size_t off = ((size_t)((b * NH + headb) * S + t)) * HD
                       + (xx >> 1) * 16 + yg * 4 + zg;
      xc[xx].x = Og[off];
      xc[xx].y = Og[off + (size_t)S * HD];
    }
  }

  #pragma unroll
  for (int a = 0; a < 8; ++a) {
    float2 r = make_float2(0.f, 0.f);
    #pragma unroll
    for (int xx = 0; xx < 8; ++xx) {
      const float w = ow0[a * 8 + xx];
      r.x = fmaf(w, xc[xx].x, r.x);
      r.y = fmaf(w, xc[xx].y, r.y);
    }
    *(float2*)&t1[(a * 8 + q) * LDT + zp * 2] = r;
  }
  __builtin_amdgcn_wave_barrier();

  float2 t1r[8];
  #pragma unroll
  for (int y = 0; y < 8; ++y)
    t1r[y] = *(float2*)&t1[(q * 8 + y) * LDT + zp * 2];
  #pragma unroll
  for (int c = 0; c < 8; ++c) {
    float2 r = make_float2(0.f, 0.f);
    #pragma unroll
    for (int y = 0; y < 8; ++y) {
      const float w = ow1[c * 8 + y];
      r.x = fmaf(w, t1r[y].x, r.x);
      r.y = fmaf(w, t1r[y].y, r.y);
    }
    *(float2*)&t2[(q * 8 + c) * LDT + zp * 2] = r;
  }
  __builtin_amdgcn_wave_barrier();

  float t2r[16];
  #pragma unroll
  for (int k = 0; k < 4; ++k)
    *(float4*)&t2r[k * 4] = *(float4*)&t2[lane * LDT + k * 4];
  float bias[16];
  #pragma unroll
  for (int k = 0; k < 4; ++k)
    *(float4*)&bias[k * 4] = *(const float4*)&ob[lane * 16 + k * 4];
  float o[16];
  #pragma unroll
  for (int d = 0; d < 16; ++d) {
    float acc = 0.f;
    #pragma unroll
    for (int j = 0; j < 16; ++j)
      acc = fmaf(ow2[d * 16 + j], t2r[j], acc);
    o[d] = acc + bias[d];
  }
  #pragma unroll
  for (int k = 0; k < 4; ++k) {
    const float4 res = make_float4(o[4 * k], o[4 * k + 1],
                                   o[4 * k + 2], o[4 * k + 3]);
    *(float4*)&out[(size_t)tok * 1024 + lane * 16 + k * 4] = res;
  }
}

// ---------------------------------------------------------------------------
extern "C" void kernel_launch(void* const* d_in, const int* in_sizes, int n_in,
                              void* d_out, int out_size, void* d_ws, size_t ws_size,
                              hipStream_t stream) {
  const float* x   = (const float*)d_in[0];
  const float* qw0 = (const float*)d_in[1];
  const float* qw1 = (const float*)d_in[2];
  const float* qw2 = (const float*)d_in[3];
  const float* qb  = (const float*)d_in[4];
  const float* kw0 = (const float*)d_in[5];
  const float* kw1 = (const float*)d_in[6];
  const float* kw2 = (const float*)d_in[7];
  const float* kb  = (const float*)d_in[8];
  const float* vw0 = (const float*)d_in[9];
  const float* vw1 = (const float*)d_in[10];
  const float* vw2 = (const float*)d_in[11];
  const float* vb  = (const float*)d_in[12];
  const float* ow0 = (const float*)d_in[13];
  const float* ow1 = (const float*)d_in[14];
  const float* ow2 = (const float*)d_in[15];
  const float* ob  = (const float*)d_in[16];

  const size_t N = (size_t)NB * NH * S * HD;  // 9,830,400 elems per logical buffer
  _Float16* Qh  = (_Float16*)d_ws;
  _Float16* Kh  = Qh + N;
  _Float16* Vth = Kh + N;
  _Float16* Vh  = Vth + N;            // row-major V temp, later reused as O
  float*    O   = (float*)Vh;
  // total ws use: 3*N*2 + N*4 = 98.3 MB

  tcl_qkv_kernel<<<dim3(NB * S / 4), 256, 0, stream>>>(
      x, qw0, qw1, qw2, qb, kw0, kw1, kw2, kb, vw0, vw1, vw2, vb, Qh, Kh, Vh);
  vtrans_kernel<<<dim3(10, NH, NB), 256, 0, stream>>>(Vh, Vth);
  attn_mfma_kernel<<<dim3(1280), 256, 0, stream>>>(Qh, Kh, Vth, O);
  tcl_out_kernel<<<dim3(NB * S / 4), 256, 0, stream>>>(O, ow0, ow1, ow2, ob,
                                                       (float*)d_out);
}

// Round 11
// 125.148 us; speedup vs baseline: 1.0464x; 1.0464x over previous
//
#include <hip/hip_runtime.h>

// Problem constants:
//   B=16, P1=25, P2=24 -> S=600 tokens; E=(8,8,16)=1024; heads (2,2,4)=16, head_dim 64
#define S   600
#define NB  16
#define NH  16
#define HD  64
// Q pre-scale: (head_dim)^-0.5 * log2(e): scores in log2 domain -> softmax uses exp2.
#define QSCALE 0.18033688011112042f

#define LDT 20   // TCL intermediate row stride (floats)

typedef _Float16 f16x8 __attribute__((ext_vector_type(8)));
typedef float f32x4 __attribute__((ext_vector_type(4)));

// ---------------------------------------------------------------------------
// Kernel A: TCL for q,k,v — wave-per-token, barrier-free (unchanged).
// ---------------------------------------------------------------------------
__global__ __launch_bounds__(256) void tcl_qkv_kernel(
    const float* __restrict__ x,
    const float* __restrict__ qw0, const float* __restrict__ qw1,
    const float* __restrict__ qw2, const float* __restrict__ qb,
    const float* __restrict__ kw0, const float* __restrict__ kw1,
    const float* __restrict__ kw2, const float* __restrict__ kb,
    const float* __restrict__ vw0, const float* __restrict__ vw1,
    const float* __restrict__ vw2, const float* __restrict__ vb,
    _Float16* __restrict__ Qh, _Float16* __restrict__ Kh,
    _Float16* __restrict__ Vh)
{
  __shared__ __align__(16) float t1s[4][64 * LDT];
  __shared__ __align__(16) float t2s[4][64 * LDT];

  const int tid = threadIdx.x;
  const int wv = tid >> 6, lane = tid & 63;
  const int tok = blockIdx.x * 4 + wv;
  const int b = tok / S, t = tok - b * S;
  const int q = lane >> 3, zp = lane & 7;
  float* __restrict__ t1 = t1s[wv];
  float* __restrict__ t2 = t2s[wv];

  float2 xc[8];
  #pragma unroll
  for (int xx = 0; xx < 8; ++xx)
    xc[xx] = *(const float2*)&x[(size_t)tok * 1024 + xx * 128 + q * 16 + zp * 2];

  const int xs = lane >> 4;
  const int h1 = (lane >> 3) & 1;
  const int cc = lane & 7;
  const int ys = cc >> 1, h2 = cc & 1;

  const float* W0[3] = {qw0, kw0, vw0};
  const float* W1[3] = {qw1, kw1, vw1};
  const float* W2[3] = {qw2, kw2, vw2};
  const float* BB[3] = {qb, kb, vb};
  _Float16* OUT[3] = {Qh, Kh, Vh};

  #pragma unroll
  for (int p = 0; p < 3; ++p) {
    const float* __restrict__ w0 = W0[p];
    const float* __restrict__ w1 = W1[p];
    const float* __restrict__ w2 = W2[p];
    const float* __restrict__ bb = BB[p];
    _Float16* __restrict__ op = OUT[p];

    #pragma unroll
    for (int a = 0; a < 8; ++a) {
      float2 r = make_float2(0.f, 0.f);
      #pragma unroll
      for (int xx = 0; xx < 8; ++xx) {
        const float w = w0[a * 8 + xx];
        r.x = fmaf(w, xc[xx].x, r.x);
        r.y = fmaf(w, xc[xx].y, r.y);
      }
      *(float2*)&t1[(a * 8 + q) * LDT + zp * 2] = r;
    }
    __builtin_amdgcn_wave_barrier();

    float2 t1r[8];
    #pragma unroll
    for (int y = 0; y < 8; ++y)
      t1r[y] = *(float2*)&t1[(q * 8 + y) * LDT + zp * 2];
    #pragma unroll
    for (int c = 0; c < 8; ++c) {
      float2 r = make_float2(0.f, 0.f);
      #pragma unroll
      for (int y = 0; y < 8; ++y) {
        const float w = w1[c * 8 + y];
        r.x = fmaf(w, t1r[y].x, r.x);
        r.y = fmaf(w, t1r[y].y, r.y);
      }
      *(float2*)&t2[(q * 8 + c) * LDT + zp * 2] = r;
    }
    __builtin_amdgcn_wave_barrier();

    float t2r[16];
    #pragma unroll
    for (int k = 0; k < 4; ++k)
      *(float4*)&t2r[k * 4] = *(float4*)&t2[lane * LDT + k * 4];
    float bias[16];
    #pragma unroll
    for (int k = 0; k < 4; ++k)
      *(float4*)&bias[k * 4] = *(const float4*)&bb[lane * 16 + k * 4];
    float o[16];
    #pragma unroll
    for (int d = 0; d < 16; ++d) {
      float acc = 0.f;
      #pragma unroll
      for (int j = 0; j < 16; ++j)
        acc = fmaf(w2[d * 16 + j], t2r[j], acc);
      o[d] = acc + bias[d];
    }
    const float sc = (p == 0) ? QSCALE : 1.0f;
    #pragma unroll
    for (int h3 = 0; h3 < 4; ++h3) {
      union { _Float16 hh[4]; uint2 u; } pk;
      #pragma unroll
      for (int z = 0; z < 4; ++z)
        pk.hh[z] = (_Float16)(o[4 * z + h3] * sc);
      const int head = h1 * 8 + h2 * 4 + h3;
      *(uint2*)&op[((size_t)((b * NH + head) * S + t)) * HD + xs * 16 + ys * 4]
          = pk.u;
    }
    __builtin_amdgcn_wave_barrier();
  }
}

// ---------------------------------------------------------------------------
// Kernel A2: V [b,h,600,64] f16 -> Vt [b,h,64,600] f16 (unchanged).
// ---------------------------------------------------------------------------
__global__ __launch_bounds__(256) void vtrans_kernel(
    const _Float16* __restrict__ Vh, _Float16* __restrict__ Vt)
{
  __shared__ __align__(16) _Float16 tile[64 * 64];
  const int tid = threadIdx.x;
  const int tt = blockIdx.x, h = blockIdx.y, b = blockIdx.z;
  const size_t rbase = (size_t)(b * NH + h) * S * HD;
  const size_t wbase = (size_t)(b * NH + h) * HD * S;
  const int t0 = tt * 64;

  #pragma unroll
  for (int hp = 0; hp < 2; ++hp) {
    const int u = hp * 256 + tid;
    const int r = u >> 3, ch = u & 7;
    f16x8 v = {0, 0, 0, 0, 0, 0, 0, 0};
    if (t0 + r < S) v = *(const f16x8*)&Vh[rbase + (size_t)(t0 + r) * HD + ch * 8];
    *(f16x8*)&tile[r * 64 + ((ch ^ ((r ^ (r >> 3)) & 7)) * 8)] = v;
  }
  __syncthreads();
  #pragma unroll
  for (int hp = 0; hp < 2; ++hp) {
    const int w = hp * 256 + tid;
    const int d = w >> 3, tc = w & 7;
    if (t0 + tc * 8 + 8 <= S) {
      const int cd = d >> 3;
      union { _Float16 hh[8]; f16x8 v; } g;
      #pragma unroll
      for (int e = 0; e < 8; ++e) {
        const int r = tc * 8 + e;
        g.hh[e] = tile[r * 64 + ((cd ^ ((r ^ (r >> 3)) & 7)) * 8) + (d & 7)];
      }
      *(f16x8*)&Vt[wbase + (size_t)d * S + t0 + tc * 8] = g.v;
    }
  }
}

// ---------------------------------------------------------------------------
// Kernel B: MFMA flash attention — R9 structure (2560 blocks, 1 frag/wave,
// 24 KB LDS) with ONE change: next-tile global loads are issued AFTER the
// second barrier, so the compiler's `s_waitcnt vmcnt(0)` before s_barrier
// drains them at the NEXT iteration's first barrier (after ~600 cy of
// compute) instead of immediately — true compute/load overlap.
// ---------------------------------------------------------------------------
template<bool TAIL>
__device__ __forceinline__ void attn_step(
    const _Float16* __restrict__ Ks, const _Float16* __restrict__ Vs,
    _Float16* __restrict__ Pw,
    const f16x8 qf0, const f16x8 qf1,
    f32x4 (&po)[4], float& mrow, float& lrow,
    const int lr, const int lg)
{
  constexpr int NMT = TAIL ? 2 : 4;
  f32x4 accs[NMT];
  #pragma unroll
  for (int mt = 0; mt < NMT; ++mt) accs[mt] = (f32x4){0.f, 0.f, 0.f, 0.f};
  __builtin_amdgcn_s_setprio(1);
  #pragma unroll
  for (int c = 0; c < 2; ++c) {
    const f16x8 qf = c ? qf1 : qf0;
    #pragma unroll
    for (int mt = 0; mt < NMT; ++mt) {
      const int krow = mt * 16 + lr;
      const f16x8 kf = *(const f16x8*)
          &Ks[krow * 64 + (((4 * c + lg) ^ (krow & 7)) * 8)];
      accs[mt] = __builtin_amdgcn_mfma_f32_16x16x32_f16(kf, qf, accs[mt], 0, 0, 0);
    }
  }
  __builtin_amdgcn_s_setprio(0);
  float sv[NMT][4];
  #pragma unroll
  for (int mt = 0; mt < NMT; ++mt)
    #pragma unroll
    for (int r = 0; r < 4; ++r) {
      float s = accs[mt][r];
      if (TAIL && mt == 1) s = (lg < 2) ? s : -1e30f;
      sv[mt][r] = s;
    }
  float tmax;
  {
    const float a = fmaxf(fmaxf(sv[0][0], sv[0][1]), fmaxf(sv[0][2], sv[0][3]));
    const float b = fmaxf(fmaxf(sv[1][0], sv[1][1]), fmaxf(sv[1][2], sv[1][3]));
    if (TAIL) {
      tmax = fmaxf(a, b);
    } else {
      const float c2 = fmaxf(fmaxf(sv[2][0], sv[2][1]), fmaxf(sv[2][2], sv[2][3]));
      const float d2 = fmaxf(fmaxf(sv[3][0], sv[3][1]), fmaxf(sv[3][2], sv[3][3]));
      tmax = fmaxf(fmaxf(a, b), fmaxf(c2, d2));
    }
  }
  tmax = fmaxf(tmax, __shfl_xor(tmax, 16));
  tmax = fmaxf(tmax, __shfl_xor(tmax, 32));
  if (!__all(tmax - mrow <= 11.0f)) {
    const float mn = fmaxf(mrow, tmax);
    const float corr = __builtin_amdgcn_exp2f(mrow - mn);
    lrow *= corr;
    #pragma unroll
    for (int dt = 0; dt < 4; ++dt) {
      po[dt][0] *= corr; po[dt][1] *= corr;
      po[dt][2] *= corr; po[dt][3] *= corr;
    }
    mrow = mn;
  }
  _Float16 ph[NMT][4];
  float rsv[NMT];
  #pragma unroll
  for (int mt = 0; mt < NMT; ++mt) {
    const float e0 = __builtin_amdgcn_exp2f(sv[mt][0] - mrow);
    const float e1 = __builtin_amdgcn_exp2f(sv[mt][1] - mrow);
    const float e2 = __builtin_amdgcn_exp2f(sv[mt][2] - mrow);
    const float e3 = __builtin_amdgcn_exp2f(sv[mt][3] - mrow);
    ph[mt][0] = (_Float16)e0; ph[mt][1] = (_Float16)e1;
    ph[mt][2] = (_Float16)e2; ph[mt][3] = (_Float16)e3;
    rsv[mt] = (e0 + e1) + (e2 + e3);
  }
  float rs = TAIL ? (rsv[0] + rsv[1]) : ((rsv[0] + rsv[1]) + (rsv[2] + rsv[3]));
  rs += __shfl_xor(rs, 16);
  rs += __shfl_xor(rs, 32);
  lrow += rs;
  #pragma unroll
  for (int mt = 0; mt < NMT; ++mt) {
    union { _Float16 hh[4]; unsigned long long u; } pk;
    pk.hh[0] = ph[mt][0]; pk.hh[1] = ph[mt][1];
    pk.hh[2] = ph[mt][2]; pk.hh[3] = ph[mt][3];
    const int idx = lr * 64 + (((2 * mt + (lg >> 1)) ^ (lr & 7)) * 8)
                  + (lg & 1) * 4;
    *(unsigned long long*)&Pw[idx] = pk.u;
  }
  __builtin_amdgcn_wave_barrier();   // fence: P writes before P reads (same wave)
  __builtin_amdgcn_s_setprio(1);
  #pragma unroll
  for (int c = 0; c < (TAIL ? 1 : 2); ++c) {
    const f16x8 pf = *(const f16x8*)&Pw[lr * 64 + (((4 * c + lg) ^ (lr & 7)) * 8)];
    #pragma unroll
    for (int dt = 0; dt < 4; ++dt) {
      const int drow = dt * 16 + lr;
      const f16x8 vf = *(const f16x8*)
          &Vs[drow * 64 + (((4 * c + lg) ^ (drow & 7)) * 8)];
      po[dt] = __builtin_amdgcn_mfma_f32_16x16x32_f16(vf, pf, po[dt], 0, 0, 0);
    }
  }
  __builtin_amdgcn_s_setprio(0);
}

__global__ __launch_bounds__(256) void attn_mfma_kernel(
    const _Float16* __restrict__ Qh, const _Float16* __restrict__ Kh,
    const _Float16* __restrict__ Vt, float* __restrict__ Og)
{
  __shared__ __align__(16) union {
    struct {
      _Float16 K[64 * 64];      // swizzled [key][d]       8 KB
      _Float16 V[64 * 64];      // swizzled [d][key]       8 KB
      _Float16 P[4][16 * 64];   // per-wave P relay        8 KB
    } m;                        // 24576 B
    float ot[4][64 * 17];       // epilogue staging (17408 B)
  } sm;

  const int tid = threadIdx.x;
  const int lane = tid & 63;
  const int wv = tid >> 6;
  // XCD-aware decode: all 10 q-tiles of a (b,h) co-locate on one XCD.
  const int id = blockIdx.x;
  const int idx = id >> 3;
  const int bh = (id & 7) * 32 + idx / 10;
  const int qt = idx - (idx / 10) * 10;
  const size_t base  = (size_t)bh * S * HD;
  const size_t vbase = (size_t)bh * HD * S;
  const int lr = lane & 15;
  const int lg = lane >> 4;

  const int qrow_l = qt * 64 + wv * 16 + lr;
  const int qrow = (qrow_l < S) ? qrow_l : (S - 1);
  const f16x8 qf0 = *(const f16x8*)&Qh[base + (size_t)qrow * HD + lg * 8];
  const f16x8 qf1 = *(const f16x8*)&Qh[base + (size_t)qrow * HD + 32 + lg * 8];

  f32x4 po[4] = {{0.f,0.f,0.f,0.f},{0.f,0.f,0.f,0.f},
                 {0.f,0.f,0.f,0.f},{0.f,0.f,0.f,0.f}};
  float mrow = -1e30f, lrow = 0.f;

  const int srow = tid >> 3, sch = tid & 7;   // staging: row 0..31, 16B chunk
  const int srow2 = srow + 32;                 // rows 32..63
  const int sswz = ((sch ^ (srow & 7)) * 8);   // srow2&7 == srow&7

  f16x8 kv[2], vv[2];
  auto stage_load_full = [&](int kt) {         // tiles 0..8: no bounds checks
    const int kb = kt * 64;
    kv[0] = *(const f16x8*)&Kh[base + (size_t)(kb + srow ) * HD + sch * 8];
    kv[1] = *(const f16x8*)&Kh[base + (size_t)(kb + srow2) * HD + sch * 8];
    vv[0] = *(const f16x8*)&Vt[vbase + (size_t)srow  * S + kb + sch * 8];
    vv[1] = *(const f16x8*)&Vt[vbase + (size_t)srow2 * S + kb + sch * 8];
  };
  auto stage_load_tail = [&]() {               // kt=9: keys 576..599 valid
    const int kb = 576;
    const f16x8 z = {0, 0, 0, 0, 0, 0, 0, 0};
    kv[0] = (srow < 24)
        ? *(const f16x8*)&Kh[base + (size_t)(kb + srow) * HD + sch * 8] : z;
    kv[1] = z;                                 // rows 32..63 all dead
    if (sch < 3) {                             // key chunks 576..599 (600%8==0)
      vv[0] = *(const f16x8*)&Vt[vbase + (size_t)srow  * S + kb + sch * 8];
      vv[1] = *(const f16x8*)&Vt[vbase + (size_t)srow2 * S + kb + sch * 8];
    } else { vv[0] = z; vv[1] = z; }
  };
  auto stage_write = [&]() {
    *(f16x8*)&sm.m.K[srow  * 64 + sswz] = kv[0];
    *(f16x8*)&sm.m.K[srow2 * 64 + sswz] = kv[1];
    *(f16x8*)&sm.m.V[srow  * 64 + sswz] = vv[0];
    *(f16x8*)&sm.m.V[srow2 * 64 + sswz] = vv[1];
  };

  stage_load_full(0);
  #pragma unroll 1
  for (int kt = 0; kt < 9; ++kt) {
    __syncthreads();     // drains tile-kt loads (issued one full tile ago)
    stage_write();
    __syncthreads();     // K/V visible; only ds_writes to drain (cheap)
    if (kt < 8) stage_load_full(kt + 1);   // issue AFTER barrier: overlaps
    else        stage_load_tail();         //   with attn_step below
    attn_step<false>(&sm.m.K[0], &sm.m.V[0], &sm.m.P[wv][0],
                     qf0, qf1, po, mrow, lrow, lr, lg);
  }
  __syncthreads();
  stage_write();
  __syncthreads();
  attn_step<true>(&sm.m.K[0], &sm.m.V[0], &sm.m.P[wv][0],
                  qf0, qf1, po, mrow, lrow, lr, lg);
  __syncthreads();   // main-loop LDS fully consumed before epilogue reuse

  const float invl = 1.0f / lrow;
  #pragma unroll
  for (int dt = 0; dt < 4; ++dt)
    #pragma unroll
    for (int r = 0; r < 4; ++r)
      sm.ot[wv][(dt * 16 + 4 * lg + r) * 17 + lr] = po[dt][r] * invl;
  __builtin_amdgcn_wave_barrier();   // fence: ot writes before ot reads (same wave)
  #pragma unroll
  for (int ps = 0; ps < 4; ++ps) {
    const int qr = ps * 4 + lg;
    const int gq = qt * 64 + wv * 16 + qr;
    if (gq < S) {
      const int d0 = lr * 4;
      float4 o4;
      o4.x = sm.ot[wv][(d0 + 0) * 17 + qr];
      o4.y = sm.ot[wv][(d0 + 1) * 17 + qr];
      o4.z = sm.ot[wv][(d0 + 2) * 17 + qr];
      o4.w = sm.ot[wv][(d0 + 3) * 17 + qr];
      *(float4*)&Og[base + (size_t)gq * HD + d0] = o4;
    }
  }
}

// ---------------------------------------------------------------------------
// Kernel C: output TCL — wave-per-token, barrier-free (unchanged).
// ---------------------------------------------------------------------------
__global__ __launch_bounds__(256) void tcl_out_kernel(
    const float* __restrict__ Og,
    const float* __restrict__ ow0, const float* __restrict__ ow1,
    const float* __restrict__ ow2, const float* __restrict__ ob,
    float* __restrict__ out)
{
  __shared__ __align__(16) float t1s[4][64 * LDT];
  __shared__ __align__(16) float t2s[4][64 * LDT];

  const int tid = threadIdx.x;
  const int wv = tid >> 6, lane = tid & 63;
  const int tok = blockIdx.x * 4 + wv;
  const int b = tok / S, t = tok - b * S;
  const int q = lane >> 3, zp = lane & 7;
  float* __restrict__ t1 = t1s[wv];
  float* __restrict__ t2 = t2s[wv];

  float2 xc[8];
  {
    const int h2g = q & 1, yg = q >> 1;
    const int h3g = 2 * (zp & 1), zg = zp >> 1;
    #pragma unroll
    for (int xx = 0; xx < 8; ++xx) {
      const int headb = (xx & 1) * 8 + h2g * 4 + h3g;
      const size_t off = ((size_t)((b * NH + headb) * S + t)) * HD
                       + (xx >> 1) * 16 + yg * 4 + zg;
      xc[xx].x = Og[off];
      xc[xx].y = Og[off + (size_t)S * HD];
    }
  }

  #pragma unroll
  for (int a = 0; a < 8; ++a) {
    float2 r = make_float2(0.f, 0.f);
    #pragma unroll
    for (int xx = 0; xx < 8; ++xx) {
      const float w = ow0[a * 8 + xx];
      r.x = fmaf(w, xc[xx].x, r.x);
      r.y = fmaf(w, xc[xx].y, r.y);
    }
    *(float2*)&t1[(a * 8 + q) * LDT + zp * 2] = r;
  }
  __builtin_amdgcn_wave_barrier();

  float2 t1r[8];
  #pragma unroll
  for (int y = 0; y < 8; ++y)
    t1r[y] = *(float2*)&t1[(q * 8 + y) * LDT + zp * 2];
  #pragma unroll
  for (int c = 0; c < 8; ++c) {
    float2 r = make_float2(0.f, 0.f);
    #pragma unroll
    for (int y = 0; y < 8; ++y) {
      const float w = ow1[c * 8 + y];
      r.x = fmaf(w, t1r[y].x, r.x);
      r.y = fmaf(w, t1r[y].y, r.y);
    }
    *(float2*)&t2[(q * 8 + c) * LDT + zp * 2] = r;
  }
  __builtin_amdgcn_wave_barrier();

  float t2r[16];
  #pragma unroll
  for (int k = 0; k < 4; ++k)
    *(float4*)&t2r[k * 4] = *(float4*)&t2[lane * LDT + k * 4];
  float bias[16];
  #pragma unroll
  for (int k = 0; k < 4; ++k)
    *(float4*)&bias[k * 4] = *(const float4*)&ob[lane * 16 + k * 4];
  float o[16];
  #pragma unroll
  for (int d = 0; d < 16; ++d) {
    float acc = 0.f;
    #pragma unroll
    for (int j = 0; j < 16; ++j)
      acc = fmaf(ow2[d * 16 + j], t2r[j], acc);
    o[d] = acc + bias[d];
  }
  #pragma unroll
  for (int k = 0; k < 4; ++k) {
    const float4 res = make_float4(o[4 * k], o[4 * k + 1],
                                   o[4 * k + 2], o[4 * k + 3]);
    *(float4*)&out[(size_t)tok * 1024 + lane * 16 + k * 4] = res;
  }
}

// ---------------------------------------------------------------------------
extern "C" void kernel_launch(void* const* d_in, const int* in_sizes, int n_in,
                              void* d_out, int out_size, void* d_ws, size_t ws_size,
                              hipStream_t stream) {
  const float* x   = (const float*)d_in[0];
  const float* qw0 = (const float*)d_in[1];
  const float* qw1 = (const float*)d_in[2];
  const float* qw2 = (const float*)d_in[3];
  const float* qb  = (const float*)d_in[4];
  const float* kw0 = (const float*)d_in[5];
  const float* kw1 = (const float*)d_in[6];
  const float* kw2 = (const float*)d_in[7];
  const float* kb  = (const float*)d_in[8];
  const float* vw0 = (const float*)d_in[9];
  const float* vw1 = (const float*)d_in[10];
  const float* vw2 = (const float*)d_in[11];
  const float* vb  = (const float*)d_in[12];
  const float* ow0 = (const float*)d_in[13];
  const float* ow1 = (const float*)d_in[14];
  const float* ow2 = (const float*)d_in[15];
  const float* ob  = (const float*)d_in[16];

  const size_t N = (size_t)NB * NH * S * HD;  // 9,830,400 elems per logical buffer
  _Float16* Qh  = (_Float16*)d_ws;
  _Float16* Kh  = Qh + N;
  _Float16* Vth = Kh + N;
  _Float16* Vh  = Vth + N;            // row-major V temp, later reused as O
  float*    O   = (float*)Vh;
  // total ws use: 3*N*2 + N*4 = 98.3 MB

  tcl_qkv_kernel<<<dim3(NB * S / 4), 256, 0, stream>>>(
      x, qw0, qw1, qw2, qb, kw0, kw1, kw2, kb, vw0, vw1, vw2, vb, Qh, Kh, Vh);
  vtrans_kernel<<<dim3(10, NH, NB), 256, 0, stream>>>(Vh, Vth);
  attn_mfma_kernel<<<dim3(2560), 256, 0, stream>>>(Qh, Kh, Vth, O);
  tcl_out_kernel<<<dim3(NB * S / 4), 256, 0, stream>>>(O, ow0, ow1, ow2, ob,
                                                       (float*)d_out);
}

// Round 12
// 119.090 us; speedup vs baseline: 1.0997x; 1.0509x over previous
//
#include <hip/hip_runtime.h>

// Problem constants:
//   B=16, P1=25, P2=24 -> S=600 tokens; E=(8,8,16)=1024; heads (2,2,4)=16, head_dim 64
#define S   600
#define NB  16
#define NH  16
#define HD  64
// Q pre-scale: (head_dim)^-0.5 * log2(e): scores in log2 domain -> softmax uses exp2.
#define QSCALE 0.18033688011112042f

#define LDT 20   // TCL intermediate row stride (floats)

typedef _Float16 f16x8 __attribute__((ext_vector_type(8)));
typedef float f32x4 __attribute__((ext_vector_type(4)));

// ---------------------------------------------------------------------------
// Kernel A: TCL for q,k,v — wave-per-token, barrier-free (unchanged).
// ---------------------------------------------------------------------------
__global__ __launch_bounds__(256) void tcl_qkv_kernel(
    const float* __restrict__ x,
    const float* __restrict__ qw0, const float* __restrict__ qw1,
    const float* __restrict__ qw2, const float* __restrict__ qb,
    const float* __restrict__ kw0, const float* __restrict__ kw1,
    const float* __restrict__ kw2, const float* __restrict__ kb,
    const float* __restrict__ vw0, const float* __restrict__ vw1,
    const float* __restrict__ vw2, const float* __restrict__ vb,
    _Float16* __restrict__ Qh, _Float16* __restrict__ Kh,
    _Float16* __restrict__ Vh)
{
  __shared__ __align__(16) float t1s[4][64 * LDT];
  __shared__ __align__(16) float t2s[4][64 * LDT];

  const int tid = threadIdx.x;
  const int wv = tid >> 6, lane = tid & 63;
  const int tok = blockIdx.x * 4 + wv;
  const int b = tok / S, t = tok - b * S;
  const int q = lane >> 3, zp = lane & 7;
  float* __restrict__ t1 = t1s[wv];
  float* __restrict__ t2 = t2s[wv];

  float2 xc[8];
  #pragma unroll
  for (int xx = 0; xx < 8; ++xx)
    xc[xx] = *(const float2*)&x[(size_t)tok * 1024 + xx * 128 + q * 16 + zp * 2];

  const int xs = lane >> 4;
  const int h1 = (lane >> 3) & 1;
  const int cc = lane & 7;
  const int ys = cc >> 1, h2 = cc & 1;

  const float* W0[3] = {qw0, kw0, vw0};
  const float* W1[3] = {qw1, kw1, vw1};
  const float* W2[3] = {qw2, kw2, vw2};
  const float* BB[3] = {qb, kb, vb};
  _Float16* OUT[3] = {Qh, Kh, Vh};

  #pragma unroll
  for (int p = 0; p < 3; ++p) {
    const float* __restrict__ w0 = W0[p];
    const float* __restrict__ w1 = W1[p];
    const float* __restrict__ w2 = W2[p];
    const float* __restrict__ bb = BB[p];
    _Float16* __restrict__ op = OUT[p];

    #pragma unroll
    for (int a = 0; a < 8; ++a) {
      float2 r = make_float2(0.f, 0.f);
      #pragma unroll
      for (int xx = 0; xx < 8; ++xx) {
        const float w = w0[a * 8 + xx];
        r.x = fmaf(w, xc[xx].x, r.x);
        r.y = fmaf(w, xc[xx].y, r.y);
      }
      *(float2*)&t1[(a * 8 + q) * LDT + zp * 2] = r;
    }
    __builtin_amdgcn_wave_barrier();

    float2 t1r[8];
    #pragma unroll
    for (int y = 0; y < 8; ++y)
      t1r[y] = *(float2*)&t1[(q * 8 + y) * LDT + zp * 2];
    #pragma unroll
    for (int c = 0; c < 8; ++c) {
      float2 r = make_float2(0.f, 0.f);
      #pragma unroll
      for (int y = 0; y < 8; ++y) {
        const float w = w1[c * 8 + y];
        r.x = fmaf(w, t1r[y].x, r.x);
        r.y = fmaf(w, t1r[y].y, r.y);
      }
      *(float2*)&t2[(q * 8 + c) * LDT + zp * 2] = r;
    }
    __builtin_amdgcn_wave_barrier();

    float t2r[16];
    #pragma unroll
    for (int k = 0; k < 4; ++k)
      *(float4*)&t2r[k * 4] = *(float4*)&t2[lane * LDT + k * 4];
    float bias[16];
    #pragma unroll
    for (int k = 0; k < 4; ++k)
      *(float4*)&bias[k * 4] = *(const float4*)&bb[lane * 16 + k * 4];
    float o[16];
    #pragma unroll
    for (int d = 0; d < 16; ++d) {
      float acc = 0.f;
      #pragma unroll
      for (int j = 0; j < 16; ++j)
        acc = fmaf(w2[d * 16 + j], t2r[j], acc);
      o[d] = acc + bias[d];
    }
    const float sc = (p == 0) ? QSCALE : 1.0f;
    #pragma unroll
    for (int h3 = 0; h3 < 4; ++h3) {
      union { _Float16 hh[4]; uint2 u; } pk;
      #pragma unroll
      for (int z = 0; z < 4; ++z)
        pk.hh[z] = (_Float16)(o[4 * z + h3] * sc);
      const int head = h1 * 8 + h2 * 4 + h3;
      *(uint2*)&op[((size_t)((b * NH + head) * S + t)) * HD + xs * 16 + ys * 4]
          = pk.u;
    }
    __builtin_amdgcn_wave_barrier();
  }
}

// ---------------------------------------------------------------------------
// Kernel A2: V [b,h,600,64] f16 -> Vt [b,h,64,600] f16 (unchanged).
// ---------------------------------------------------------------------------
__global__ __launch_bounds__(256) void vtrans_kernel(
    const _Float16* __restrict__ Vh, _Float16* __restrict__ Vt)
{
  __shared__ __align__(16) _Float16 tile[64 * 64];
  const int tid = threadIdx.x;
  const int tt = blockIdx.x, h = blockIdx.y, b = blockIdx.z;
  const size_t rbase = (size_t)(b * NH + h) * S * HD;
  const size_t wbase = (size_t)(b * NH + h) * HD * S;
  const int t0 = tt * 64;

  #pragma unroll
  for (int hp = 0; hp < 2; ++hp) {
    const int u = hp * 256 + tid;
    const int r = u >> 3, ch = u & 7;
    f16x8 v = {0, 0, 0, 0, 0, 0, 0, 0};
    if (t0 + r < S) v = *(const f16x8*)&Vh[rbase + (size_t)(t0 + r) * HD + ch * 8];
    *(f16x8*)&tile[r * 64 + ((ch ^ ((r ^ (r >> 3)) & 7)) * 8)] = v;
  }
  __syncthreads();
  #pragma unroll
  for (int hp = 0; hp < 2; ++hp) {
    const int w = hp * 256 + tid;
    const int d = w >> 3, tc = w & 7;
    if (t0 + tc * 8 + 8 <= S) {
      const int cd = d >> 3;
      union { _Float16 hh[8]; f16x8 v; } g;
      #pragma unroll
      for (int e = 0; e < 8; ++e) {
        const int r = tc * 8 + e;
        g.hh[e] = tile[r * 64 + ((cd ^ ((r ^ (r >> 3)) & 7)) * 8) + (d & 7)];
      }
      *(f16x8*)&Vt[wbase + (size_t)d * S + t0 + tc * 8] = g.v;
    }
  }
}

// ---------------------------------------------------------------------------
// Kernel B: MFMA flash attention — global_load_lds staging (width=16),
// double-buffered K/V, ONE barrier per tile. LDS dest is linear per wave
// (uniform base + lane*16); the XOR swizzle is preserved by pre-swizzling
// the per-lane GLOBAL source chunk (chunk = ss^sr, an involution; each
// 8-lane group still covers one contiguous 128B row -> coalesced).
// Tail tile: K garbage rows are lane-exactly masked; V garbage slots
// (keys >= 600) are explicitly zeroed (garbage*0 could be NaN).
// ---------------------------------------------------------------------------
__device__ __forceinline__ void gload16(const _Float16* g, _Float16* l) {
  __builtin_amdgcn_global_load_lds(
      (const __attribute__((address_space(1))) unsigned int*)g,
      (__attribute__((address_space(3))) unsigned int*)l, 16, 0, 0);
}

template<bool TAIL>
__device__ __forceinline__ void attn_step(
    const _Float16* __restrict__ Ks, const _Float16* __restrict__ Vs,
    _Float16* __restrict__ Pw,
    const f16x8 qf0, const f16x8 qf1,
    f32x4 (&po)[4], float& mrow, float& lrow,
    const int lr, const int lg)
{
  constexpr int NMT = TAIL ? 2 : 4;
  f32x4 accs[NMT];
  #pragma unroll
  for (int mt = 0; mt < NMT; ++mt) accs[mt] = (f32x4){0.f, 0.f, 0.f, 0.f};
  __builtin_amdgcn_s_setprio(1);
  #pragma unroll
  for (int c = 0; c < 2; ++c) {
    const f16x8 qf = c ? qf1 : qf0;
    #pragma unroll
    for (int mt = 0; mt < NMT; ++mt) {
      const int krow = mt * 16 + lr;
      const f16x8 kf = *(const f16x8*)
          &Ks[krow * 64 + (((4 * c + lg) ^ (krow & 7)) * 8)];
      accs[mt] = __builtin_amdgcn_mfma_f32_16x16x32_f16(kf, qf, accs[mt], 0, 0, 0);
    }
  }
  __builtin_amdgcn_s_setprio(0);
  float sv[NMT][4];
  #pragma unroll
  for (int mt = 0; mt < NMT; ++mt)
    #pragma unroll
    for (int r = 0; r < 4; ++r) {
      float s = accs[mt][r];
      if (TAIL && mt == 1) s = (lg < 2) ? s : -1e30f;
      sv[mt][r] = s;
    }
  float tmax;
  {
    const float a = fmaxf(fmaxf(sv[0][0], sv[0][1]), fmaxf(sv[0][2], sv[0][3]));
    const float b = fmaxf(fmaxf(sv[1][0], sv[1][1]), fmaxf(sv[1][2], sv[1][3]));
    if (TAIL) {
      tmax = fmaxf(a, b);
    } else {
      const float c2 = fmaxf(fmaxf(sv[2][0], sv[2][1]), fmaxf(sv[2][2], sv[2][3]));
      const float d2 = fmaxf(fmaxf(sv[3][0], sv[3][1]), fmaxf(sv[3][2], sv[3][3]));
      tmax = fmaxf(fmaxf(a, b), fmaxf(c2, d2));
    }
  }
  tmax = fmaxf(tmax, __shfl_xor(tmax, 16));
  tmax = fmaxf(tmax, __shfl_xor(tmax, 32));
  if (!__all(tmax - mrow <= 11.0f)) {
    const float mn = fmaxf(mrow, tmax);
    const float corr = __builtin_amdgcn_exp2f(mrow - mn);
    lrow *= corr;
    #pragma unroll
    for (int dt = 0; dt < 4; ++dt) {
      po[dt][0] *= corr; po[dt][1] *= corr;
      po[dt][2] *= corr; po[dt][3] *= corr;
    }
    mrow = mn;
  }
  _Float16 ph[NMT][4];
  float rsv[NMT];
  #pragma unroll
  for (int mt = 0; mt < NMT; ++mt) {
    const float e0 = __builtin_amdgcn_exp2f(sv[mt][0] - mrow);
    const float e1 = __builtin_amdgcn_exp2f(sv[mt][1] - mrow);
    const float e2 = __builtin_amdgcn_exp2f(sv[mt][2] - mrow);
    const float e3 = __builtin_amdgcn_exp2f(sv[mt][3] - mrow);
    ph[mt][0] = (_Float16)e0; ph[mt][1] = (_Float16)e1;
    ph[mt][2] = (_Float16)e2; ph[mt][3] = (_Float16)e3;
    rsv[mt] = (e0 + e1) + (e2 + e3);
  }
  float rs = TAIL ? (rsv[0] + rsv[1]) : ((rsv[0] + rsv[1]) + (rsv[2] + rsv[3]));
  rs += __shfl_xor(rs, 16);
  rs += __shfl_xor(rs, 32);
  lrow += rs;
  #pragma unroll
  for (int mt = 0; mt < NMT; ++mt) {
    union { _Float16 hh[4]; unsigned long long u; } pk;
    pk.hh[0] = ph[mt][0]; pk.hh[1] = ph[mt][1];
    pk.hh[2] = ph[mt][2]; pk.hh[3] = ph[mt][3];
    const int idx = lr * 64 + (((2 * mt + (lg >> 1)) ^ (lr & 7)) * 8)
                  + (lg & 1) * 4;
    *(unsigned long long*)&Pw[idx] = pk.u;
  }
  __builtin_amdgcn_wave_barrier();   // fence: P writes before P reads (same wave)
  __builtin_amdgcn_s_setprio(1);
  #pragma unroll
  for (int c = 0; c < (TAIL ? 1 : 2); ++c) {
    const f16x8 pf = *(const f16x8*)&Pw[lr * 64 + (((4 * c + lg) ^ (lr & 7)) * 8)];
    #pragma unroll
    for (int dt = 0; dt < 4; ++dt) {
      const int drow = dt * 16 + lr;
      const f16x8 vf = *(const f16x8*)
          &Vs[drow * 64 + (((4 * c + lg) ^ (drow & 7)) * 8)];
      po[dt] = __builtin_amdgcn_mfma_f32_16x16x32_f16(vf, pf, po[dt], 0, 0, 0);
    }
  }
  __builtin_amdgcn_s_setprio(0);
}

__global__ __launch_bounds__(256, 4) void attn_mfma_kernel(
    const _Float16* __restrict__ Qh, const _Float16* __restrict__ Kh,
    const _Float16* __restrict__ Vt, float* __restrict__ Og)
{
  __shared__ __align__(16) union {
    struct {
      _Float16 K[2][64 * 64];   // dbuf, swizzled [key][d]  16 KB
      _Float16 V[2][64 * 64];   // dbuf, swizzled [d][key]  16 KB
      _Float16 P[4][16 * 64];   // per-wave P relay          8 KB
    } m;                        // 40960 B -> 4 blocks/CU
    float ot[4][64 * 17];       // epilogue staging (17408 B)
  } sm;

  const int tid = threadIdx.x;
  const int lane = tid & 63;
  const int wv = tid >> 6;
  // XCD-aware decode: all 10 q-tiles of a (b,h) co-locate on one XCD.
  const int id = blockIdx.x;
  const int idx = id >> 3;
  const int bh = (id & 7) * 32 + idx / 10;
  const int qt = idx - (idx / 10) * 10;
  const size_t base  = (size_t)bh * S * HD;
  const size_t vbase = (size_t)bh * HD * S;
  const int lr = lane & 15;
  const int lg = lane >> 4;

  const int qrow_l = qt * 64 + wv * 16 + lr;
  const int qrow = (qrow_l < S) ? qrow_l : (S - 1);
  const f16x8 qf0 = *(const f16x8*)&Qh[base + (size_t)qrow * HD + lg * 8];
  const f16x8 qf1 = *(const f16x8*)&Qh[base + (size_t)qrow * HD + 32 + lg * 8];

  f32x4 po[4] = {{0.f,0.f,0.f,0.f},{0.f,0.f,0.f,0.f},
                 {0.f,0.f,0.f,0.f},{0.f,0.f,0.f,0.f}};
  float mrow = -1e30f, lrow = 0.f;

  // global_load_lds staging: wave wv owns 8-row chunks {wv, wv+4} of K and V.
  // Lane l = (sr, ss): linear LDS slot (row sr, slot ss) receives global
  // chunk (ss^sr) -> LDS holds the same XOR-swizzled layout as before.
  const int sr = lane >> 3, ss = lane & 7;
  const int swz8 = (ss ^ sr) * 8;
  const int c0 = wv, c1 = wv + 4;
  const _Float16* kg0 = Kh + base + (size_t)(c0 * 8 + sr) * HD + swz8;
  const _Float16* kg1 = Kh + base + (size_t)(c1 * 8 + sr) * HD + swz8;
  const _Float16* vg0 = Vt + vbase + (size_t)(c0 * 8 + sr) * S + swz8;
  const _Float16* vg1 = Vt + vbase + (size_t)(c1 * 8 + sr) * S + swz8;

  auto gload_tile = [&](int kt, int b) {
    const int kb = kt * 64;
    gload16(kg0 + (size_t)kb * HD, &sm.m.K[b][c0 * 512]);
    gload16(kg1 + (size_t)kb * HD, &sm.m.K[b][c1 * 512]);
    gload16(vg0 + kb, &sm.m.V[b][c0 * 512]);
    gload16(vg1 + kb, &sm.m.V[b][c1 * 512]);
  };

  gload_tile(0, 0);
  #pragma unroll 2
  for (int kt = 0; kt < 9; ++kt) {
    const int b = kt & 1;
    __syncthreads();              // drains tile-kt gloads; orders buf^1 WAR
    gload_tile(kt + 1, b ^ 1);    // streams during attn_step below
    attn_step<false>(&sm.m.K[b][0], &sm.m.V[b][0], &sm.m.P[wv][0],
                     qf0, qf1, po, mrow, lrow, lr, lg);
  }
  __syncthreads();                // tile-9 gload drained (landed in buf 1)
  // zero V slots holding key-chunks 3..7 (keys 600..639: garbage, and
  // garbage * P=0 could be NaN). Slot for (row, kc) = kc ^ (row & 7).
  for (int u = tid; u < 320; u += 256) {
    const int row = u / 5, kc = 3 + u % 5;
    *(f16x8*)&sm.m.V[1][row * 64 + ((kc ^ (row & 7)) * 8)] =
        (f16x8){0, 0, 0, 0, 0, 0, 0, 0};
  }
  __syncthreads();                // zeros visible to all waves
  attn_step<true>(&sm.m.K[1][0], &sm.m.V[1][0], &sm.m.P[wv][0],
                  qf0, qf1, po, mrow, lrow, lr, lg);
  __syncthreads();   // main-loop LDS fully consumed before epilogue reuse

  const float invl = 1.0f / lrow;
  #pragma unroll
  for (int dt = 0; dt < 4; ++dt)
    #pragma unroll
    for (int r = 0; r < 4; ++r)
      sm.ot[wv][(dt * 16 + 4 * lg + r) * 17 + lr] = po[dt][r] * invl;
  __builtin_amdgcn_wave_barrier();   // fence: ot writes before ot reads (same wave)
  #pragma unroll
  for (int ps = 0; ps < 4; ++ps) {
    const int qr = ps * 4 + lg;
    const int gq = qt * 64 + wv * 16 + qr;
    if (gq < S) {
      const int d0 = lr * 4;
      float4 o4;
      o4.x = sm.ot[wv][(d0 + 0) * 17 + qr];
      o4.y = sm.ot[wv][(d0 + 1) * 17 + qr];
      o4.z = sm.ot[wv][(d0 + 2) * 17 + qr];
      o4.w = sm.ot[wv][(d0 + 3) * 17 + qr];
      *(float4*)&Og[base + (size_t)gq * HD + d0] = o4;
    }
  }
}

// ---------------------------------------------------------------------------
// Kernel C: output TCL — wave-per-token, barrier-free (unchanged).
// ---------------------------------------------------------------------------
__global__ __launch_bounds__(256) void tcl_out_kernel(
    const float* __restrict__ Og,
    const float* __restrict__ ow0, const float* __restrict__ ow1,
    const float* __restrict__ ow2, const float* __restrict__ ob,
    float* __restrict__ out)
{
  __shared__ __align__(16) float t1s[4][64 * LDT];
  __shared__ __align__(16) float t2s[4][64 * LDT];

  const int tid = threadIdx.x;
  const int wv = tid >> 6, lane = tid & 63;
  const int tok = blockIdx.x * 4 + wv;
  const int b = tok / S, t = tok - b * S;
  const int q = lane >> 3, zp = lane & 7;
  float* __restrict__ t1 = t1s[wv];
  float* __restrict__ t2 = t2s[wv];

  float2 xc[8];
  {
    const int h2g = q & 1, yg = q >> 1;
    const int h3g = 2 * (zp & 1), zg = zp >> 1;
    #pragma unroll
    for (int xx = 0; xx < 8; ++xx) {
      const int headb = (xx & 1) * 8 + h2g * 4 + h3g;
      const size_t off = ((size_t)((b * NH + headb) * S + t)) * HD
                       + (xx >> 1) * 16 + yg * 4 + zg;
      xc[xx].x = Og[off];
      xc[xx].y = Og[off + (size_t)S * HD];
    }
  }

  #pragma unroll
  for (int a = 0; a < 8; ++a) {
    float2 r = make_float2(0.f, 0.f);
    #pragma unroll
    for (int xx = 0; xx < 8; ++xx) {
      const float w = ow0[a * 8 + xx];
      r.x = fmaf(w, xc[xx].x, r.x);
      r.y = fmaf(w, xc[xx].y, r.y);
    }
    *(float2*)&t1[(a * 8 + q) * LDT + zp * 2] = r;
  }
  __builtin_amdgcn_wave_barrier();

  float2 t1r[8];
  #pragma unroll
  for (int y = 0; y < 8; ++y)
    t1r[y] = *(float2*)&t1[(q * 8 + y) * LDT + zp * 2];
  #pragma unroll
  for (int c = 0; c < 8; ++c) {
    float2 r = make_float2(0.f, 0.f);
    #pragma unroll
    for (int y = 0; y < 8; ++y) {
      const float w = ow1[c * 8 + y];
      r.x = fmaf(w, t1r[y].x, r.x);
      r.y = fmaf(w, t1r[y].y, r.y);
    }
    *(float2*)&t2[(q * 8 + c) * LDT + zp * 2] = r;
  }
  __builtin_amdgcn_wave_barrier();

  float t2r[16];
  #pragma unroll
  for (int k = 0; k < 4; ++k)
    *(float4*)&t2r[k * 4] = *(float4*)&t2[lane * LDT + k * 4];
  float bias[16];
  #pragma unroll
  for (int k = 0; k < 4; ++k)
    *(float4*)&bias[k * 4] = *(const float4*)&ob[lane * 16 + k * 4];
  float o[16];
  #pragma unroll
  for (int d = 0; d < 16; ++d) {
    float acc = 0.f;
    #pragma unroll
    for (int j = 0; j < 16; ++j)
      acc = fmaf(ow2[d * 16 + j], t2r[j], acc);
    o[d] = acc + bias[d];
  }
  #pragma unroll
  for (int k = 0; k < 4; ++k) {
    const float4 res = make_float4(o[4 * k], o[4 * k + 1],
                                   o[4 * k + 2], o[4 * k + 3]);
    *(float4*)&out[(size_t)tok * 1024 + lane * 16 + k * 4] = res;
  }
}

// ---------------------------------------------------------------------------
extern "C" void kernel_launch(void* const* d_in, const int* in_sizes, int n_in,
                              void* d_out, int out_size, void* d_ws, size_t ws_size,
                              hipStream_t stream) {
  const float* x   = (const float*)d_in[0];
  const float* qw0 = (const float*)d_in[1];
  const float* qw1 = (const float*)d_in[2];
  const float* qw2 = (const float*)d_in[3];
  const float* qb  = (const float*)d_in[4];
  const float* kw0 = (const float*)d_in[5];
  const float* kw1 = (const float*)d_in[6];
  const float* kw2 = (const float*)d_in[7];
  const float* kb  = (const float*)d_in[8];
  const float* vw0 = (const float*)d_in[9];
  const float* vw1 = (const float*)d_in[10];
  const float* vw2 = (const float*)d_in[11];
  const float* vb  = (const float*)d_in[12];
  const float* ow0 = (const float*)d_in[13];
  const float* ow1 = (const float*)d_in[14];
  const float* ow2 = (const float*)d_in[15];
  const float* ob  = (const float*)d_in[16];

  const size_t N = (size_t)NB * NH * S * HD;  // 9,830,400 elems per logical buffer
  _Float16* Qh  = (_Float16*)d_ws;
  _Float16* Kh  = Qh + N;
  _Float16* Vth = Kh + N;
  _Float16* Vh  = Vth + N;            // row-major V temp, later reused as O
  float*    O   = (float*)Vh;
  // total ws use: 3*N*2 + N*4 = 98.3 MB

  tcl_qkv_kernel<<<dim3(NB * S / 4), 256, 0, stream>>>(
      x, qw0, qw1, qw2, qb, kw0, kw1, kw2, kb, vw0, vw1, vw2, vb, Qh, Kh, Vh);
  vtrans_kernel<<<dim3(10, NH, NB), 256, 0, stream>>>(Vh, Vth);
  attn_mfma_kernel<<<dim3(2560), 256, 0, stream>>>(Qh, Kh, Vth, O);
  tcl_out_kernel<<<dim3(NB * S / 4), 256, 0, stream>>>(O, ow0, ow1, ow2, ob,
                                                       (float*)d_out);
}